// Round 7
// baseline (109094.788 us; speedup 1.0000x reference)
//
#include <hip/hip_runtime.h>
#include <hip/hip_bf16.h>
#include <math.h>

typedef unsigned long long u64;

// Sizes
#define N_NODES 8192
#define IN_DIM 64
#define MLP_HID 128
#define EMB 512
#define HID 1024
#define G3 (3*HID)   // 3072
#define SEQ 8192

// ---------------------------------------------------------------------------
// Expert MLP: one block per node. h1 = relu(x@W1[t]+b1[t]); emb = h1@W2[t]+b2[t]
// ---------------------------------------------------------------------------
__global__ __launch_bounds__(256) void mlp_kernel(
    const float* __restrict__ x, const int* __restrict__ types,
    const float* __restrict__ W1, const float* __restrict__ b1,
    const float* __restrict__ W2, const float* __restrict__ b2,
    float* __restrict__ emb)
{
    __shared__ float xs[IN_DIM];
    __shared__ float h1[MLP_HID];
    const int n = blockIdx.x;
    const int ty = types[n];
    const int tid = threadIdx.x;

    if (tid < IN_DIM) xs[tid] = x[n * IN_DIM + tid];
    __syncthreads();

    if (tid < MLP_HID) {
        const float* w = W1 + (size_t)ty * IN_DIM * MLP_HID;
        float acc = b1[ty * MLP_HID + tid];
        #pragma unroll 8
        for (int k = 0; k < IN_DIM; k++)
            acc += xs[k] * w[k * MLP_HID + tid];
        h1[tid] = fmaxf(acc, 0.f);
    }
    __syncthreads();

    const float* w2 = W2 + (size_t)ty * MLP_HID * EMB;
    #pragma unroll
    for (int j = tid; j < EMB; j += 256) {
        float acc = b2[ty * EMB + j];
        #pragma unroll 8
        for (int k = 0; k < MLP_HID; k++)
            acc += h1[k] * w2[k * EMB + j];
        emb[(size_t)n * EMB + j] = acc;
    }
}

// ---------------------------------------------------------------------------
// C[M,N] = A[M,K] @ B[N,K]^T + bias[N]   (fp32, 64x64 tile, BK=16)
// ---------------------------------------------------------------------------
#define BM 64
#define BN 64
#define BK 16
__global__ __launch_bounds__(256) void gemm_bt_bias(
    const float* __restrict__ A, const float* __restrict__ B,
    const float* __restrict__ bias, float* __restrict__ C,
    int M, int N, int K)
{
    __shared__ float As[BK][BM + 1];
    __shared__ float Bs[BK][BN + 1];
    const int bm = blockIdx.y * BM, bn = blockIdx.x * BN;
    const int tid = threadIdx.x;
    const int tx = tid & 15, tyy = tid >> 4;   // 16x16 thread grid
    const int lr = tid >> 2;                   // loader row 0..63
    const int lk = (tid & 3) * 4;              // loader k offset

    float acc[4][4] = {};

    for (int k0 = 0; k0 < K; k0 += BK) {
        float4 av = *(const float4*)(A + (size_t)(bm + lr) * K + k0 + lk);
        float4 bv = *(const float4*)(B + (size_t)(bn + lr) * K + k0 + lk);
        As[lk + 0][lr] = av.x; As[lk + 1][lr] = av.y;
        As[lk + 2][lr] = av.z; As[lk + 3][lr] = av.w;
        Bs[lk + 0][lr] = bv.x; Bs[lk + 1][lr] = bv.y;
        Bs[lk + 2][lr] = bv.z; Bs[lk + 3][lr] = bv.w;
        __syncthreads();
        #pragma unroll
        for (int k = 0; k < BK; k++) {
            float a[4], b[4];
            #pragma unroll
            for (int i = 0; i < 4; i++) a[i] = As[k][tyy * 4 + i];
            #pragma unroll
            for (int j = 0; j < 4; j++) b[j] = Bs[k][tx * 4 + j];
            #pragma unroll
            for (int i = 0; i < 4; i++)
                #pragma unroll
                for (int j = 0; j < 4; j++)
                    acc[i][j] += a[i] * b[j];
        }
        __syncthreads();
    }

    #pragma unroll
    for (int i = 0; i < 4; i++) {
        const int row = bm + tyy * 4 + i;
        #pragma unroll
        for (int j = 0; j < 4; j++) {
            const int col = bn + tx * 4 + j;
            C[(size_t)row * N + col] = acc[i][j] + bias[col];
        }
    }
}

// ---------------------------------------------------------------------------
// Fused 2-layer GRU scan. 256 blocks (1/CU); block b's wave wv owns dim
// d = 4b+wv of both layers. Weights LDS-resident (R5).
//
// R6/R7 sync design (R3-R5 plateaued ~4 us/epoch; FETCH invariance proved
// the exchange chain, not weight streaming, is the critical path):
//  - values published with fire-and-forget atomicExch: RMWs execute AT the
//    coherence point, so consumer loads don't snoop a remote dirty L2.
//  - per-wave notification: lane0 posts a RELEASE agent-scope fetch_add
//    (release on the RMW = per-wave vmcnt drain of its own exchs, ordered
//    before the counter bump). No end-of-epoch __syncthreads in the chain.
//  - value prefetch overlapped with the counter-gate spin; after the gate
//    only late words re-poll. Per-word tag spin remains the correctness
//    ground truth (gate is advisory).
// Anti-lap: a wave's epoch-e add is issued only after its hnew (which
// data-depends, via S2 + LDS, on every thread's epoch-(e-1) value loads)
// is computed, so all-counters==target(e) implies all epoch-(e-1) reads
// retired; overwriting ring slot (e&1) in the depth-2 ring is then safe.
// ---------------------------------------------------------------------------
#define WLDS_FLOATS (36 * 1024)          // 147456 B
#define HL0_OFF WLDS_FLOATS
#define HL1_OFF (WLDS_FLOATS + HID)
#define NCNT 16

__global__ __launch_bounds__(256, 1) void gru_fused(
    const float* __restrict__ gi0,   // [T, 3072] layer-0 input gates (incl. bih0)
    const float* __restrict__ Whh0, const float* __restrict__ bhh0,
    const float* __restrict__ Wih1, const float* __restrict__ bih1,
    const float* __restrict__ Whh1, const float* __restrict__ bhh1,
    const float* __restrict__ h_init,   // [2, 1024]
    u64* __restrict__ hbuf0,            // [2][1024] tagged ring, layer 0
    u64* __restrict__ hbuf1,            // [2][1024] tagged ring, layer 1
    int* __restrict__ counters,         // [16] at stride 64 ints, zeroed
    float* __restrict__ hout,           // [1024] final h1
    int T)
{
    __shared__ float lds[WLDS_FLOATS + 2 * HID];   // 155648 B

    const int tid = threadIdx.x;
    const int b = blockIdx.x;
    const int wv = tid >> 6;
    const int lane = tid & 63;
    const int d = b * 4 + wv;

    float* hl0 = &lds[HL0_OFF];
    float* hl1 = &lds[HL1_OFF];

    // ---- stage 36 weight rows into LDS (once) ----
    for (int p = 0; p < 36; p++) {
        const int dl = p / 9, r = p % 9;
        const int m = r / 3, g = r % 3;
        const float* src = (m == 0 ? Whh0 : (m == 1 ? Wih1 : Whh1))
                           + (size_t)(g * HID + b * 4 + dl) * HID;
        float4* dst = (float4*)&lds[(dl * 9 + r) * HID];
        dst[tid] = ((const float4*)src)[tid];
    }
    __syncthreads();

    const float bh00 = bhh0[d], bh01 = bhh0[HID + d], bh02 = bhh0[2 * HID + d];
    const float bi10 = bih1[d], bi11 = bih1[HID + d], bi12 = bih1[2 * HID + d];
    const float bh10 = bhh1[d], bh11 = bhh1[HID + d], bh12 = bhh1[2 * HID + d];

    float hprev0 = 0.f, hprev1 = 0.f;
    float gc0 = 0.f, gc1 = 0.f, gc2 = 0.f;
    if (lane == 0) {
        hprev0 = h_init[d];
        hprev1 = h_init[HID + d];
        gc0 = gi0[d]; gc1 = gi0[HID + d]; gc2 = gi0[2 * HID + d];
    }

    for (int e = 1; e <= T + 1; e++) {
        // Prefetch next epoch's gi0 row (hidden under the gate wait).
        float gn0 = 0.f, gn1 = 0.f, gn2 = 0.f;
        if (lane == 0 && e < T) {
            const float* g = gi0 + (size_t)e * G3;
            gn0 = g[d]; gn1 = g[HID + d]; gn2 = g[2 * HID + d];
        }

        if (e == 1) {
            #pragma unroll
            for (int j = 0; j < 4; j++)
                hl0[tid + 256 * j] = h_init[tid + 256 * j];
            __syncthreads();
        } else {
            const unsigned te = (unsigned)(e - 1);
            const u64* sa = hbuf0 + ((e - 1) & 1) * HID;
            const u64* sb = hbuf1 + ((e - 1) & 1) * HID;

            // Value PREFETCH — issued before/during the gate spin.
            u64 va[4], vb[4];
            #pragma unroll
            for (int j = 0; j < 4; j++)
                va[j] = __hip_atomic_load(&sa[tid + 256 * j], __ATOMIC_RELAXED,
                                          __HIP_MEMORY_SCOPE_AGENT);
            #pragma unroll
            for (int j = 0; j < 4; j++)
                vb[j] = __hip_atomic_load(&sb[tid + 256 * j], __ATOMIC_RELAXED,
                                          __HIP_MEMORY_SCOPE_AGENT);

            // Gate: thread0 spins on the 16 counters (advisory).
            if (tid == 0) {
                const int target = (e - 1) * 64;
                bool ready;
                do {
                    ready = true;
                    #pragma unroll
                    for (int j = 0; j < NCNT; j++) {
                        int c = __hip_atomic_load(&counters[j * 64],
                                                  __ATOMIC_RELAXED,
                                                  __HIP_MEMORY_SCOPE_AGENT);
                        ready &= (c >= target);
                    }
                } while (!ready);
            }
            __syncthreads();   // S1

            // Tag check; re-poll only late words (ground truth).
            #pragma unroll
            for (int j = 0; j < 4; j++)
                while ((unsigned)(va[j] >> 32) != te)
                    va[j] = __hip_atomic_load(&sa[tid + 256 * j], __ATOMIC_RELAXED,
                                              __HIP_MEMORY_SCOPE_AGENT);
            #pragma unroll
            for (int j = 0; j < 4; j++)
                while ((unsigned)(vb[j] >> 32) != te)
                    vb[j] = __hip_atomic_load(&sb[tid + 256 * j], __ATOMIC_RELAXED,
                                              __HIP_MEMORY_SCOPE_AGENT);
            #pragma unroll
            for (int j = 0; j < 4; j++) {
                hl0[tid + 256 * j] = __uint_as_float((unsigned)va[j]);
                hl1[tid + 256 * j] = __uint_as_float((unsigned)vb[j]);
            }
            __syncthreads();   // S2: LDS ready
        }

        // h fragments: lane L covers cols {256j + 4L + k}.
        const float4* h0v4 = (const float4*)hl0;
        const float4* h1v4 = (const float4*)hl1;
        float4 hr0[4], hr1[4];
        #pragma unroll
        for (int j = 0; j < 4; j++) hr0[j] = h0v4[64 * j + lane];
        if (e > 1) {
            #pragma unroll
            for (int j = 0; j < 4; j++) hr1[j] = h1v4[64 * j + lane];
        }

        // ---- layer 0 ----
        if (e <= T) {
            float s[3];
            #pragma unroll
            for (int g = 0; g < 3; g++) {
                const float4* wr = (const float4*)&lds[(wv * 9 + g) * HID];
                float4 a = {0.f, 0.f, 0.f, 0.f};
                #pragma unroll
                for (int j = 0; j < 4; j++) {
                    float4 w = wr[64 * j + lane];
                    a.x += w.x * hr0[j].x; a.y += w.y * hr0[j].y;
                    a.z += w.z * hr0[j].z; a.w += w.w * hr0[j].w;
                }
                float acc = (a.x + a.y) + (a.z + a.w);
                #pragma unroll
                for (int off = 32; off; off >>= 1)
                    acc += __shfl_down(acc, off, 64);
                s[g] = acc;
            }
            if (lane == 0) {
                const float r = 1.f / (1.f + __expf(-(gc0 + s[0] + bh00)));
                const float z = 1.f / (1.f + __expf(-(gc1 + s[1] + bh01)));
                const float nn = tanhf(gc2 + r * (s[2] + bh02));
                const float hnew = (1.f - z) * nn + z * hprev0;
                hprev0 = hnew;
                const u64 v = ((u64)(unsigned)e << 32) | (u64)__float_as_uint(hnew);
                (void)__hip_atomic_exchange(&hbuf0[(e & 1) * HID + d], v,
                                            __ATOMIC_RELAXED, __HIP_MEMORY_SCOPE_AGENT);
                gc0 = gn0; gc1 = gn1; gc2 = gn2;
            }
        }

        // ---- layer 1 ----
        if (e == 1) {
            if (lane == 0) {
                const u64 v = ((u64)1u << 32) | (u64)__float_as_uint(hprev1);
                (void)__hip_atomic_exchange(&hbuf1[HID + d], v,
                                            __ATOMIC_RELAXED, __HIP_MEMORY_SCOPE_AGENT);
            }
        } else {
            float si[3], sh[3];
            #pragma unroll
            for (int g = 0; g < 3; g++) {
                const float4* wi = (const float4*)&lds[(wv * 9 + 3 + g) * HID];
                const float4* wh = (const float4*)&lds[(wv * 9 + 6 + g) * HID];
                float4 a = {0.f, 0.f, 0.f, 0.f};
                float4 c = {0.f, 0.f, 0.f, 0.f};
                #pragma unroll
                for (int j = 0; j < 4; j++) {
                    float4 w1 = wi[64 * j + lane];
                    float4 w2 = wh[64 * j + lane];
                    a.x += w1.x * hr0[j].x; a.y += w1.y * hr0[j].y;
                    a.z += w1.z * hr0[j].z; a.w += w1.w * hr0[j].w;
                    c.x += w2.x * hr1[j].x; c.y += w2.y * hr1[j].y;
                    c.z += w2.z * hr1[j].z; c.w += w2.w * hr1[j].w;
                }
                float ai = (a.x + a.y) + (a.z + a.w);
                float ch = (c.x + c.y) + (c.z + c.w);
                #pragma unroll
                for (int off = 32; off; off >>= 1) {
                    ai += __shfl_down(ai, off, 64);
                    ch += __shfl_down(ch, off, 64);
                }
                si[g] = ai; sh[g] = ch;
            }
            if (lane == 0) {
                const float r = 1.f / (1.f + __expf(-(si[0] + bi10 + sh[0] + bh10)));
                const float z = 1.f / (1.f + __expf(-(si[1] + bi11 + sh[1] + bh11)));
                const float nn = tanhf(si[2] + bi12 + r * (sh[2] + bh12));
                const float hnew = (1.f - z) * nn + z * hprev1;
                hprev1 = hnew;
                if (e <= T) {
                    const u64 v = ((u64)(unsigned)e << 32) | (u64)__float_as_uint(hnew);
                    (void)__hip_atomic_exchange(&hbuf1[(e & 1) * HID + d], v,
                                                __ATOMIC_RELAXED, __HIP_MEMORY_SCOPE_AGENT);
                } else {
                    hout[d] = hnew;   // e == T+1: final h1
                }
            }
        }

        // Per-wave notification: RELEASE add orders this wave's exchs
        // (vmcnt drain) before the counter bump. No block-wide barrier.
        if (lane == 0 && e <= T) {
            __hip_atomic_fetch_add(&counters[(d & (NCNT - 1)) * 64], 1,
                                   __ATOMIC_RELEASE, __HIP_MEMORY_SCOPE_AGENT);
        }
    }
}

// ---------------------------------------------------------------------------
// out[o] = dot(fc_W[o,:], h) + fc_b[o]; 64 waves, 16 outputs each.
// ---------------------------------------------------------------------------
__global__ __launch_bounds__(256) void fc_kernel(
    const float* __restrict__ h, const float* __restrict__ W,
    const float* __restrict__ b, float* __restrict__ out)
{
    __shared__ float hs[HID];
    const int wv = blockIdx.x * 4 + (threadIdx.x >> 6);
    const int lane = threadIdx.x & 63;
    for (int i = threadIdx.x; i < HID; i += 256) hs[i] = h[i];
    __syncthreads();
    for (int o = wv * 16; o < wv * 16 + 16; o++) {
        float acc = 0.f;
        #pragma unroll
        for (int u = 0; u < 16; u++)
            acc += W[(size_t)o * HID + lane + 64 * u] * hs[lane + 64 * u];
        #pragma unroll
        for (int off = 32; off; off >>= 1)
            acc += __shfl_down(acc, off, 64);
        if (lane == 0) out[o] = acc + b[o];
    }
}

// ---------------------------------------------------------------------------
extern "C" void kernel_launch(void* const* d_in, const int* in_sizes, int n_in,
                              void* d_out, int out_size, void* d_ws, size_t ws_size,
                              hipStream_t stream)
{
    const float* node_feats = (const float*)d_in[0];
    const int*   node_types = (const int*)d_in[1];
    const float* W1   = (const float*)d_in[2];
    const float* b1   = (const float*)d_in[3];
    const float* W2   = (const float*)d_in[4];
    const float* b2   = (const float*)d_in[5];
    const float* Wih0 = (const float*)d_in[6];
    const float* Whh0 = (const float*)d_in[7];
    const float* bih0 = (const float*)d_in[8];
    const float* bhh0 = (const float*)d_in[9];
    const float* Wih1 = (const float*)d_in[10];
    const float* Whh1 = (const float*)d_in[11];
    const float* bih1 = (const float*)d_in[12];
    const float* bhh1 = (const float*)d_in[13];
    const float* h_init = (const float*)d_in[14];
    const float* fc_W = (const float*)d_in[15];
    const float* fc_b = (const float*)d_in[16];
    float* out = (float*)d_out;

    char* ws = (char*)d_ws;
    const size_t GI_OFF    = 0;                      // 8192*3072*4 = 100663296
    const size_t EMB_OFF   = 100663296;              // 8192*512*4  = 16777216
    const size_t HOUT_OFF  = 117440512;              // 1024*4      = 4096
    const size_t HBUF0_OFF = 117444608;              // 2048*8      = 16384
    const size_t HBUF1_OFF = 117460992;              // 2048*8      = 16384
    const size_t CNT_OFF   = 117477376;              // 16*64*4     = 4096

    float* gi   = (float*)(ws + GI_OFF);
    float* emb  = (float*)(ws + EMB_OFF);
    float* hout = (float*)(ws + HOUT_OFF);
    u64* hbuf0  = (u64*)(ws + HBUF0_OFF);
    u64* hbuf1  = (u64*)(ws + HBUF1_OFF);
    int* cnts   = (int*)(ws + CNT_OFF);
    // hbufs start 0xAA-poisoned: tag 0xAAAAAAAA never matches an epoch.
    // Counters must start at 0.
    (void)hipMemsetAsync(ws + CNT_OFF, 0, 4096, stream);

    // 1. Expert MLP -> emb [8192, 512]
    mlp_kernel<<<N_NODES, 256, 0, stream>>>(node_feats, node_types, W1, b1, W2, b2, emb);

    // 2. gi0 = emb @ Wih0^T + bih0  [8192, 3072]
    gemm_bt_bias<<<dim3(G3 / BN, N_NODES / BM), 256, 0, stream>>>(
        emb, Wih0, bih0, gi, N_NODES, G3, EMB);

    // 3. fused 2-layer scan (weights LDS-resident, exch-published values)
    gru_fused<<<256, 256, 0, stream>>>(gi, Whh0, bhh0, Wih1, bih1, Whh1, bhh1,
                                       h_init, hbuf0, hbuf1, cnts, hout, SEQ);

    // 4. FC on final hidden state
    fc_kernel<<<16, 256, 0, stream>>>(hout, fc_W, fc_b, out);
}

// Round 8
// 32752.219 us; speedup vs baseline: 3.3309x; 3.3309x over previous
//
#include <hip/hip_runtime.h>
#include <hip/hip_bf16.h>
#include <math.h>

typedef unsigned long long u64;

// Sizes
#define N_NODES 8192
#define IN_DIM 64
#define MLP_HID 128
#define EMB 512
#define HID 1024
#define G3 (3*HID)   // 3072
#define SEQ 8192

// ---------------------------------------------------------------------------
// Expert MLP: one block per node. h1 = relu(x@W1[t]+b1[t]); emb = h1@W2[t]+b2[t]
// ---------------------------------------------------------------------------
__global__ __launch_bounds__(256) void mlp_kernel(
    const float* __restrict__ x, const int* __restrict__ types,
    const float* __restrict__ W1, const float* __restrict__ b1,
    const float* __restrict__ W2, const float* __restrict__ b2,
    float* __restrict__ emb)
{
    __shared__ float xs[IN_DIM];
    __shared__ float h1[MLP_HID];
    const int n = blockIdx.x;
    const int ty = types[n];
    const int tid = threadIdx.x;

    if (tid < IN_DIM) xs[tid] = x[n * IN_DIM + tid];
    __syncthreads();

    if (tid < MLP_HID) {
        const float* w = W1 + (size_t)ty * IN_DIM * MLP_HID;
        float acc = b1[ty * MLP_HID + tid];
        #pragma unroll 8
        for (int k = 0; k < IN_DIM; k++)
            acc += xs[k] * w[k * MLP_HID + tid];
        h1[tid] = fmaxf(acc, 0.f);
    }
    __syncthreads();

    const float* w2 = W2 + (size_t)ty * MLP_HID * EMB;
    #pragma unroll
    for (int j = tid; j < EMB; j += 256) {
        float acc = b2[ty * EMB + j];
        #pragma unroll 8
        for (int k = 0; k < MLP_HID; k++)
            acc += h1[k] * w2[k * EMB + j];
        emb[(size_t)n * EMB + j] = acc;
    }
}

// ---------------------------------------------------------------------------
// C[M,N] = A[M,K] @ B[N,K]^T + bias[N]   (fp32, 64x64 tile, BK=16)
// ---------------------------------------------------------------------------
#define BM 64
#define BN 64
#define BK 16
__global__ __launch_bounds__(256) void gemm_bt_bias(
    const float* __restrict__ A, const float* __restrict__ B,
    const float* __restrict__ bias, float* __restrict__ C,
    int M, int N, int K)
{
    __shared__ float As[BK][BM + 1];
    __shared__ float Bs[BK][BN + 1];
    const int bm = blockIdx.y * BM, bn = blockIdx.x * BN;
    const int tid = threadIdx.x;
    const int tx = tid & 15, tyy = tid >> 4;   // 16x16 thread grid
    const int lr = tid >> 2;                   // loader row 0..63
    const int lk = (tid & 3) * 4;              // loader k offset

    float acc[4][4] = {};

    for (int k0 = 0; k0 < K; k0 += BK) {
        float4 av = *(const float4*)(A + (size_t)(bm + lr) * K + k0 + lk);
        float4 bv = *(const float4*)(B + (size_t)(bn + lr) * K + k0 + lk);
        As[lk + 0][lr] = av.x; As[lk + 1][lr] = av.y;
        As[lk + 2][lr] = av.z; As[lk + 3][lr] = av.w;
        Bs[lk + 0][lr] = bv.x; Bs[lk + 1][lr] = bv.y;
        Bs[lk + 2][lr] = bv.z; Bs[lk + 3][lr] = bv.w;
        __syncthreads();
        #pragma unroll
        for (int k = 0; k < BK; k++) {
            float a[4], b[4];
            #pragma unroll
            for (int i = 0; i < 4; i++) a[i] = As[k][tyy * 4 + i];
            #pragma unroll
            for (int j = 0; j < 4; j++) b[j] = Bs[k][tx * 4 + j];
            #pragma unroll
            for (int i = 0; i < 4; i++)
                #pragma unroll
                for (int j = 0; j < 4; j++)
                    acc[i][j] += a[i] * b[j];
        }
        __syncthreads();
    }

    #pragma unroll
    for (int i = 0; i < 4; i++) {
        const int row = bm + tyy * 4 + i;
        #pragma unroll
        for (int j = 0; j < 4; j++) {
            const int col = bn + tx * 4 + j;
            C[(size_t)row * N + col] = acc[i][j] + bias[col];
        }
    }
}

// ---------------------------------------------------------------------------
// Fused 2-layer GRU scan. 256 blocks (1/CU); block b's wave wv owns dim
// d = 4b+wv of both layers. Weights LDS-resident (R5).
//
// R8 sync: NO counter gate (R4/R5's gate added a serial hop for no gain;
// R7's release-RMW notification regressed 3x). Publication = plain relaxed
// agent-scope 8B atomic store of (epoch<<32 | value) into a depth-2 ring.
// Discovery = PARALLEL re-poll rounds: issue all 8 tagged loads (single
// vmcnt wait), check all tags, repeat. This replaces R3-R5's 8 serial
// per-word spin loops (~8 dependent RTTs -> epoch-time scaled with polled
// word count: R2 4w=2.5us, R3-R5 8w=3.9-4.3us). Expected ~1-2 rounds.
// Anti-lap (R3's proven argument): a block posts tag e only after S2, i.e.
// after ALL its threads saw all 2048 tags==e-1, which implies every block's
// epoch-(e-2) values were fully read before any slot is overwritten.
// ---------------------------------------------------------------------------
#define WLDS_FLOATS (36 * 1024)          // 147456 B
#define HL0_OFF WLDS_FLOATS
#define HL1_OFF (WLDS_FLOATS + HID)

__global__ __launch_bounds__(256, 1) void gru_fused(
    const float* __restrict__ gi0,   // [T, 3072] layer-0 input gates (incl. bih0)
    const float* __restrict__ Whh0, const float* __restrict__ bhh0,
    const float* __restrict__ Wih1, const float* __restrict__ bih1,
    const float* __restrict__ Whh1, const float* __restrict__ bhh1,
    const float* __restrict__ h_init,   // [2, 1024]
    u64* __restrict__ hbuf0,            // [2][1024] tagged ring, layer 0
    u64* __restrict__ hbuf1,            // [2][1024] tagged ring, layer 1
    float* __restrict__ hout,           // [1024] final h1
    int T)
{
    __shared__ float lds[WLDS_FLOATS + 2 * HID];   // 155648 B

    const int tid = threadIdx.x;
    const int b = blockIdx.x;
    const int wv = tid >> 6;
    const int lane = tid & 63;
    const int d = b * 4 + wv;

    float* hl0 = &lds[HL0_OFF];
    float* hl1 = &lds[HL1_OFF];

    // ---- stage 36 weight rows into LDS (once) ----
    for (int p = 0; p < 36; p++) {
        const int dl = p / 9, r = p % 9;
        const int m = r / 3, g = r % 3;
        const float* src = (m == 0 ? Whh0 : (m == 1 ? Wih1 : Whh1))
                           + (size_t)(g * HID + b * 4 + dl) * HID;
        float4* dst = (float4*)&lds[(dl * 9 + r) * HID];
        dst[tid] = ((const float4*)src)[tid];
    }
    __syncthreads();

    const float bh00 = bhh0[d], bh01 = bhh0[HID + d], bh02 = bhh0[2 * HID + d];
    const float bi10 = bih1[d], bi11 = bih1[HID + d], bi12 = bih1[2 * HID + d];
    const float bh10 = bhh1[d], bh11 = bhh1[HID + d], bh12 = bhh1[2 * HID + d];

    float hprev0 = 0.f, hprev1 = 0.f;
    float gc0 = 0.f, gc1 = 0.f, gc2 = 0.f;
    if (lane == 0) {
        hprev0 = h_init[d];
        hprev1 = h_init[HID + d];
        gc0 = gi0[d]; gc1 = gi0[HID + d]; gc2 = gi0[2 * HID + d];
    }

    for (int e = 1; e <= T + 1; e++) {
        // Prefetch next epoch's gi0 row (hidden under the poll wait).
        float gn0 = 0.f, gn1 = 0.f, gn2 = 0.f;
        if (lane == 0 && e < T) {
            const float* g = gi0 + (size_t)e * G3;
            gn0 = g[d]; gn1 = g[HID + d]; gn2 = g[2 * HID + d];
        }

        if (e == 1) {
            #pragma unroll
            for (int j = 0; j < 4; j++)
                hl0[tid + 256 * j] = h_init[tid + 256 * j];
            __syncthreads();
        } else {
            const unsigned te = (unsigned)(e - 1);
            const u64* sa = hbuf0 + ((e - 1) & 1) * HID;
            const u64* sb = hbuf1 + ((e - 1) & 1) * HID;
            u64 va[4], vb[4];

            // PARALLEL re-poll: all 8 loads in flight per round, one vmcnt
            // wait, one combined check. ~1-2 rounds instead of 8 serial RTTs.
            for (;;) {
                #pragma unroll
                for (int j = 0; j < 4; j++)
                    va[j] = __hip_atomic_load(&sa[tid + 256 * j], __ATOMIC_RELAXED,
                                              __HIP_MEMORY_SCOPE_AGENT);
                #pragma unroll
                for (int j = 0; j < 4; j++)
                    vb[j] = __hip_atomic_load(&sb[tid + 256 * j], __ATOMIC_RELAXED,
                                              __HIP_MEMORY_SCOPE_AGENT);
                bool ok = true;
                #pragma unroll
                for (int j = 0; j < 4; j++) {
                    ok &= ((unsigned)(va[j] >> 32) == te);
                    ok &= ((unsigned)(vb[j] >> 32) == te);
                }
                if (ok) break;
            }
            #pragma unroll
            for (int j = 0; j < 4; j++) {
                hl0[tid + 256 * j] = __uint_as_float((unsigned)va[j]);
                hl1[tid + 256 * j] = __uint_as_float((unsigned)vb[j]);
            }
            __syncthreads();   // S2: LDS ready; all threads' polls complete
        }

        // h fragments: lane L covers cols {256j + 4L + k}.
        const float4* h0v4 = (const float4*)hl0;
        const float4* h1v4 = (const float4*)hl1;
        float4 hr0[4], hr1[4];
        #pragma unroll
        for (int j = 0; j < 4; j++) hr0[j] = h0v4[64 * j + lane];
        if (e > 1) {
            #pragma unroll
            for (int j = 0; j < 4; j++) hr1[j] = h1v4[64 * j + lane];
        }

        // ---- layer 0 ----
        if (e <= T) {
            float s[3];
            #pragma unroll
            for (int g = 0; g < 3; g++) {
                const float4* wr = (const float4*)&lds[(wv * 9 + g) * HID];
                float4 a = {0.f, 0.f, 0.f, 0.f};
                #pragma unroll
                for (int j = 0; j < 4; j++) {
                    float4 w = wr[64 * j + lane];
                    a.x += w.x * hr0[j].x; a.y += w.y * hr0[j].y;
                    a.z += w.z * hr0[j].z; a.w += w.w * hr0[j].w;
                }
                float acc = (a.x + a.y) + (a.z + a.w);
                #pragma unroll
                for (int off = 32; off; off >>= 1)
                    acc += __shfl_down(acc, off, 64);
                s[g] = acc;
            }
            if (lane == 0) {
                const float r = 1.f / (1.f + __expf(-(gc0 + s[0] + bh00)));
                const float z = 1.f / (1.f + __expf(-(gc1 + s[1] + bh01)));
                const float nn = tanhf(gc2 + r * (s[2] + bh02));
                const float hnew = (1.f - z) * nn + z * hprev0;
                hprev0 = hnew;
                const u64 v = ((u64)(unsigned)e << 32) | (u64)__float_as_uint(hnew);
                __hip_atomic_store(&hbuf0[(e & 1) * HID + d], v,
                                   __ATOMIC_RELAXED, __HIP_MEMORY_SCOPE_AGENT);
                gc0 = gn0; gc1 = gn1; gc2 = gn2;
            }
        }

        // ---- layer 1 ----
        if (e == 1) {
            if (lane == 0) {
                const u64 v = ((u64)1u << 32) | (u64)__float_as_uint(hprev1);
                __hip_atomic_store(&hbuf1[HID + d], v,
                                   __ATOMIC_RELAXED, __HIP_MEMORY_SCOPE_AGENT);
            }
        } else {
            float si[3], sh[3];
            #pragma unroll
            for (int g = 0; g < 3; g++) {
                const float4* wi = (const float4*)&lds[(wv * 9 + 3 + g) * HID];
                const float4* wh = (const float4*)&lds[(wv * 9 + 6 + g) * HID];
                float4 a = {0.f, 0.f, 0.f, 0.f};
                float4 c = {0.f, 0.f, 0.f, 0.f};
                #pragma unroll
                for (int j = 0; j < 4; j++) {
                    float4 w1 = wi[64 * j + lane];
                    float4 w2 = wh[64 * j + lane];
                    a.x += w1.x * hr0[j].x; a.y += w1.y * hr0[j].y;
                    a.z += w1.z * hr0[j].z; a.w += w1.w * hr0[j].w;
                    c.x += w2.x * hr1[j].x; c.y += w2.y * hr1[j].y;
                    c.z += w2.z * hr1[j].z; c.w += w2.w * hr1[j].w;
                }
                float ai = (a.x + a.y) + (a.z + a.w);
                float ch = (c.x + c.y) + (c.z + c.w);
                #pragma unroll
                for (int off = 32; off; off >>= 1) {
                    ai += __shfl_down(ai, off, 64);
                    ch += __shfl_down(ch, off, 64);
                }
                si[g] = ai; sh[g] = ch;
            }
            if (lane == 0) {
                const float r = 1.f / (1.f + __expf(-(si[0] + bi10 + sh[0] + bh10)));
                const float z = 1.f / (1.f + __expf(-(si[1] + bi11 + sh[1] + bh11)));
                const float nn = tanhf(si[2] + bi12 + r * (sh[2] + bh12));
                const float hnew = (1.f - z) * nn + z * hprev1;
                hprev1 = hnew;
                if (e <= T) {
                    const u64 v = ((u64)(unsigned)e << 32) | (u64)__float_as_uint(hnew);
                    __hip_atomic_store(&hbuf1[(e & 1) * HID + d], v,
                                       __ATOMIC_RELAXED, __HIP_MEMORY_SCOPE_AGENT);
                } else {
                    hout[d] = hnew;   // e == T+1: final h1
                }
            }
        }
    }
}

// ---------------------------------------------------------------------------
// out[o] = dot(fc_W[o,:], h) + fc_b[o]; 64 waves, 16 outputs each.
// ---------------------------------------------------------------------------
__global__ __launch_bounds__(256) void fc_kernel(
    const float* __restrict__ h, const float* __restrict__ W,
    const float* __restrict__ b, float* __restrict__ out)
{
    __shared__ float hs[HID];
    const int wv = blockIdx.x * 4 + (threadIdx.x >> 6);
    const int lane = threadIdx.x & 63;
    for (int i = threadIdx.x; i < HID; i += 256) hs[i] = h[i];
    __syncthreads();
    for (int o = wv * 16; o < wv * 16 + 16; o++) {
        float acc = 0.f;
        #pragma unroll
        for (int u = 0; u < 16; u++)
            acc += W[(size_t)o * HID + lane + 64 * u] * hs[lane + 64 * u];
        #pragma unroll
        for (int off = 32; off; off >>= 1)
            acc += __shfl_down(acc, off, 64);
        if (lane == 0) out[o] = acc + b[o];
    }
}

// ---------------------------------------------------------------------------
extern "C" void kernel_launch(void* const* d_in, const int* in_sizes, int n_in,
                              void* d_out, int out_size, void* d_ws, size_t ws_size,
                              hipStream_t stream)
{
    const float* node_feats = (const float*)d_in[0];
    const int*   node_types = (const int*)d_in[1];
    const float* W1   = (const float*)d_in[2];
    const float* b1   = (const float*)d_in[3];
    const float* W2   = (const float*)d_in[4];
    const float* b2   = (const float*)d_in[5];
    const float* Wih0 = (const float*)d_in[6];
    const float* Whh0 = (const float*)d_in[7];
    const float* bih0 = (const float*)d_in[8];
    const float* bhh0 = (const float*)d_in[9];
    const float* Wih1 = (const float*)d_in[10];
    const float* Whh1 = (const float*)d_in[11];
    const float* bih1 = (const float*)d_in[12];
    const float* bhh1 = (const float*)d_in[13];
    const float* h_init = (const float*)d_in[14];
    const float* fc_W = (const float*)d_in[15];
    const float* fc_b = (const float*)d_in[16];
    float* out = (float*)d_out;

    char* ws = (char*)d_ws;
    const size_t GI_OFF    = 0;                      // 8192*3072*4 = 100663296
    const size_t EMB_OFF   = 100663296;              // 8192*512*4  = 16777216
    const size_t HOUT_OFF  = 117440512;              // 1024*4      = 4096
    const size_t HBUF0_OFF = 117444608;              // 2048*8      = 16384
    const size_t HBUF1_OFF = 117460992;              // 2048*8      = 16384

    float* gi   = (float*)(ws + GI_OFF);
    float* emb  = (float*)(ws + EMB_OFF);
    float* hout = (float*)(ws + HOUT_OFF);
    u64* hbuf0  = (u64*)(ws + HBUF0_OFF);
    u64* hbuf1  = (u64*)(ws + HBUF1_OFF);
    // hbufs start 0xAA-poisoned: tag 0xAAAAAAAA never matches an epoch in
    // [1, 8193], so no memset needed anywhere.

    // 1. Expert MLP -> emb [8192, 512]
    mlp_kernel<<<N_NODES, 256, 0, stream>>>(node_feats, node_types, W1, b1, W2, b2, emb);

    // 2. gi0 = emb @ Wih0^T + bih0  [8192, 3072]
    gemm_bt_bias<<<dim3(G3 / BN, N_NODES / BM), 256, 0, stream>>>(
        emb, Wih0, bih0, gi, N_NODES, G3, EMB);

    // 3. fused 2-layer scan (weights LDS-resident, parallel re-poll exchange)
    gru_fused<<<256, 256, 0, stream>>>(gi, Whh0, bhh0, Wih1, bih1, Whh1, bhh1,
                                       h_init, hbuf0, hbuf1, hout, SEQ);

    // 4. FC on final hidden state
    fc_kernel<<<16, 256, 0, stream>>>(hout, fc_W, fc_b, out);
}

// Round 9
// 30808.875 us; speedup vs baseline: 3.5410x; 1.0631x over previous
//
#include <hip/hip_runtime.h>
#include <hip/hip_bf16.h>
#include <math.h>

typedef unsigned long long u64;

// Sizes
#define N_NODES 8192
#define IN_DIM 64
#define MLP_HID 128
#define EMB 512
#define HID 1024
#define G3 (3*HID)   // 3072
#define SEQ 8192

// ---------------------------------------------------------------------------
// Expert MLP: one block per node. h1 = relu(x@W1[t]+b1[t]); emb = h1@W2[t]+b2[t]
// ---------------------------------------------------------------------------
__global__ __launch_bounds__(256) void mlp_kernel(
    const float* __restrict__ x, const int* __restrict__ types,
    const float* __restrict__ W1, const float* __restrict__ b1,
    const float* __restrict__ W2, const float* __restrict__ b2,
    float* __restrict__ emb)
{
    __shared__ float xs[IN_DIM];
    __shared__ float h1[MLP_HID];
    const int n = blockIdx.x;
    const int ty = types[n];
    const int tid = threadIdx.x;

    if (tid < IN_DIM) xs[tid] = x[n * IN_DIM + tid];
    __syncthreads();

    if (tid < MLP_HID) {
        const float* w = W1 + (size_t)ty * IN_DIM * MLP_HID;
        float acc = b1[ty * MLP_HID + tid];
        #pragma unroll 8
        for (int k = 0; k < IN_DIM; k++)
            acc += xs[k] * w[k * MLP_HID + tid];
        h1[tid] = fmaxf(acc, 0.f);
    }
    __syncthreads();

    const float* w2 = W2 + (size_t)ty * MLP_HID * EMB;
    #pragma unroll
    for (int j = tid; j < EMB; j += 256) {
        float acc = b2[ty * EMB + j];
        #pragma unroll 8
        for (int k = 0; k < MLP_HID; k++)
            acc += h1[k] * w2[k * EMB + j];
        emb[(size_t)n * EMB + j] = acc;
    }
}

// ---------------------------------------------------------------------------
// C[M,N] = A[M,K] @ B[N,K]^T + bias[N]   (fp32, 64x64 tile, BK=16)
// ---------------------------------------------------------------------------
#define BM 64
#define BN 64
#define BK 16
__global__ __launch_bounds__(256) void gemm_bt_bias(
    const float* __restrict__ A, const float* __restrict__ B,
    const float* __restrict__ bias, float* __restrict__ C,
    int M, int N, int K)
{
    __shared__ float As[BK][BM + 1];
    __shared__ float Bs[BK][BN + 1];
    const int bm = blockIdx.y * BM, bn = blockIdx.x * BN;
    const int tid = threadIdx.x;
    const int tx = tid & 15, tyy = tid >> 4;   // 16x16 thread grid
    const int lr = tid >> 2;                   // loader row 0..63
    const int lk = (tid & 3) * 4;              // loader k offset

    float acc[4][4] = {};

    for (int k0 = 0; k0 < K; k0 += BK) {
        float4 av = *(const float4*)(A + (size_t)(bm + lr) * K + k0 + lk);
        float4 bv = *(const float4*)(B + (size_t)(bn + lr) * K + k0 + lk);
        As[lk + 0][lr] = av.x; As[lk + 1][lr] = av.y;
        As[lk + 2][lr] = av.z; As[lk + 3][lr] = av.w;
        Bs[lk + 0][lr] = bv.x; Bs[lk + 1][lr] = bv.y;
        Bs[lk + 2][lr] = bv.z; Bs[lk + 3][lr] = bv.w;
        __syncthreads();
        #pragma unroll
        for (int k = 0; k < BK; k++) {
            float a[4], b[4];
            #pragma unroll
            for (int i = 0; i < 4; i++) a[i] = As[k][tyy * 4 + i];
            #pragma unroll
            for (int j = 0; j < 4; j++) b[j] = Bs[k][tx * 4 + j];
            #pragma unroll
            for (int i = 0; i < 4; i++)
                #pragma unroll
                for (int j = 0; j < 4; j++)
                    acc[i][j] += a[i] * b[j];
        }
        __syncthreads();
    }

    #pragma unroll
    for (int i = 0; i < 4; i++) {
        const int row = bm + tyy * 4 + i;
        #pragma unroll
        for (int j = 0; j < 4; j++) {
            const int col = bn + tx * 4 + j;
            C[(size_t)row * N + col] = acc[i][j] + bias[col];
        }
    }
}

// ---------------------------------------------------------------------------
// Fused 2-layer GRU scan. 256 blocks (1/CU); block b's wave wv owns dim
// d = 4b+wv of both layers. Weights LDS-resident (R5).
//
// R9 sync: SPLIT-PHASE exchange. Layer-0's recurrence is the only true
// serial chain, so each epoch: poll hbuf0 (4 words/thread) -> compute &
// publish h0 -> poll hbuf1 -> compute & publish h1. Layer-1's exchange
// hides in layer-0's shadow. Polls are parallel rounds with a PENDING MASK
// (only un-tagged words reload) and s_sleep(1) backoff after a failed
// round — keeps the 1-RTT latency shape of R8's parallel poll while
// avoiding its congestion collapse (R8 showed 49-73ms dispatch variance).
// Publication: plain relaxed agent-scope 8B store (epoch<<32|bits),
// depth-2 ring (proven absmax=0.0 since R4).
// Anti-lap per buffer: block X posts tag e into slot e&1 only after S1/S2,
// i.e. after ALL X's threads saw every tag e-1 — and any block Y posted
// tag e-1 only after Y's S1/S2 guaranteed Y's tag e-2 reads (same slot)
// retired. Barriers: S1 after hl0 fill, S2 after hl1 fill; hr0 reads
// precede S2, hr1 reads precede next epoch's S1, so LDS reuse is race-free.
// ---------------------------------------------------------------------------
#define WLDS_FLOATS (36 * 1024)          // 147456 B
#define HL0_OFF WLDS_FLOATS
#define HL1_OFF (WLDS_FLOATS + HID)

__global__ __launch_bounds__(256, 1) void gru_fused(
    const float* __restrict__ gi0,   // [T, 3072] layer-0 input gates (incl. bih0)
    const float* __restrict__ Whh0, const float* __restrict__ bhh0,
    const float* __restrict__ Wih1, const float* __restrict__ bih1,
    const float* __restrict__ Whh1, const float* __restrict__ bhh1,
    const float* __restrict__ h_init,   // [2, 1024]
    u64* __restrict__ hbuf0,            // [2][1024] tagged ring, layer 0
    u64* __restrict__ hbuf1,            // [2][1024] tagged ring, layer 1
    float* __restrict__ hout,           // [1024] final h1
    int T)
{
    __shared__ float lds[WLDS_FLOATS + 2 * HID];   // 155648 B

    const int tid = threadIdx.x;
    const int b = blockIdx.x;
    const int wv = tid >> 6;
    const int lane = tid & 63;
    const int d = b * 4 + wv;

    float* hl0 = &lds[HL0_OFF];
    float* hl1 = &lds[HL1_OFF];

    // ---- stage 36 weight rows into LDS (once) ----
    for (int p = 0; p < 36; p++) {
        const int dl = p / 9, r = p % 9;
        const int m = r / 3, g = r % 3;
        const float* src = (m == 0 ? Whh0 : (m == 1 ? Wih1 : Whh1))
                           + (size_t)(g * HID + b * 4 + dl) * HID;
        float4* dst = (float4*)&lds[(dl * 9 + r) * HID];
        dst[tid] = ((const float4*)src)[tid];
    }
    __syncthreads();

    const float bh00 = bhh0[d], bh01 = bhh0[HID + d], bh02 = bhh0[2 * HID + d];
    const float bi10 = bih1[d], bi11 = bih1[HID + d], bi12 = bih1[2 * HID + d];
    const float bh10 = bhh1[d], bh11 = bhh1[HID + d], bh12 = bhh1[2 * HID + d];

    float hprev0 = 0.f, hprev1 = 0.f;
    float gc0 = 0.f, gc1 = 0.f, gc2 = 0.f;
    if (lane == 0) {
        hprev0 = h_init[d];
        hprev1 = h_init[HID + d];
        gc0 = gi0[d]; gc1 = gi0[HID + d]; gc2 = gi0[2 * HID + d];
    }

    for (int e = 1; e <= T + 1; e++) {
        // Prefetch next epoch's gi0 row (in flight under the polls).
        float gn0 = 0.f, gn1 = 0.f, gn2 = 0.f;
        if (lane == 0 && e < T) {
            const float* g = gi0 + (size_t)e * G3;
            gn0 = g[d]; gn1 = g[HID + d]; gn2 = g[2 * HID + d];
        }

        // ===== PHASE A: layer-0 h exchange (critical chain) =====
        if (e == 1) {
            #pragma unroll
            for (int j = 0; j < 4; j++)
                hl0[tid + 256 * j] = h_init[tid + 256 * j];
            __syncthreads();   // S1
        } else {
            const unsigned te = (unsigned)(e - 1);
            const u64* sa = hbuf0 + ((e - 1) & 1) * HID;
            u64 va[4];
            bool dn[4] = {false, false, false, false};
            for (;;) {
                #pragma unroll
                for (int j = 0; j < 4; j++)
                    if (!dn[j])
                        va[j] = __hip_atomic_load(&sa[tid + 256 * j], __ATOMIC_RELAXED,
                                                  __HIP_MEMORY_SCOPE_AGENT);
                bool ok = true;
                #pragma unroll
                for (int j = 0; j < 4; j++) {
                    dn[j] = dn[j] || ((unsigned)(va[j] >> 32) == te);
                    ok &= dn[j];
                }
                if (ok) break;
                __builtin_amdgcn_s_sleep(1);   // backoff: tame the poll storm
            }
            #pragma unroll
            for (int j = 0; j < 4; j++)
                hl0[tid + 256 * j] = __uint_as_float((unsigned)va[j]);
            __syncthreads();   // S1: all poll0 loads retired block-wide
        }

        const float4* h0v4 = (const float4*)hl0;
        float4 hr0[4];
        #pragma unroll
        for (int j = 0; j < 4; j++) hr0[j] = h0v4[64 * j + lane];

        // ===== PHASE B: layer-0 compute + publish =====
        if (e <= T) {
            float s[3];
            #pragma unroll
            for (int g = 0; g < 3; g++) {
                const float4* wr = (const float4*)&lds[(wv * 9 + g) * HID];
                float4 a = {0.f, 0.f, 0.f, 0.f};
                #pragma unroll
                for (int j = 0; j < 4; j++) {
                    float4 w = wr[64 * j + lane];
                    a.x += w.x * hr0[j].x; a.y += w.y * hr0[j].y;
                    a.z += w.z * hr0[j].z; a.w += w.w * hr0[j].w;
                }
                float acc = (a.x + a.y) + (a.z + a.w);
                #pragma unroll
                for (int off = 32; off; off >>= 1)
                    acc += __shfl_down(acc, off, 64);
                s[g] = acc;
            }
            if (lane == 0) {
                const float r = 1.f / (1.f + __expf(-(gc0 + s[0] + bh00)));
                const float z = 1.f / (1.f + __expf(-(gc1 + s[1] + bh01)));
                const float nn = tanhf(gc2 + r * (s[2] + bh02));
                const float hnew = (1.f - z) * nn + z * hprev0;
                hprev0 = hnew;
                const u64 v = ((u64)(unsigned)e << 32) | (u64)__float_as_uint(hnew);
                __hip_atomic_store(&hbuf0[(e & 1) * HID + d], v,
                                   __ATOMIC_RELAXED, __HIP_MEMORY_SCOPE_AGENT);
                gc0 = gn0; gc1 = gn1; gc2 = gn2;
            }
        }

        // ===== PHASE C: layer-1 h exchange (in layer-0's shadow) =====
        if (e == 1) {
            if (lane == 0) {
                const u64 v = ((u64)1u << 32) | (u64)__float_as_uint(hprev1);
                __hip_atomic_store(&hbuf1[HID + d], v,
                                   __ATOMIC_RELAXED, __HIP_MEMORY_SCOPE_AGENT);
            }
            __syncthreads();   // protect hl0 reads vs next epoch's writes
        } else {
            const unsigned te = (unsigned)(e - 1);
            const u64* sb = hbuf1 + ((e - 1) & 1) * HID;
            u64 vb[4];
            bool dn[4] = {false, false, false, false};
            for (;;) {
                #pragma unroll
                for (int j = 0; j < 4; j++)
                    if (!dn[j])
                        vb[j] = __hip_atomic_load(&sb[tid + 256 * j], __ATOMIC_RELAXED,
                                                  __HIP_MEMORY_SCOPE_AGENT);
                bool ok = true;
                #pragma unroll
                for (int j = 0; j < 4; j++) {
                    dn[j] = dn[j] || ((unsigned)(vb[j] >> 32) == te);
                    ok &= dn[j];
                }
                if (ok) break;
                __builtin_amdgcn_s_sleep(1);
            }
            #pragma unroll
            for (int j = 0; j < 4; j++)
                hl1[tid + 256 * j] = __uint_as_float((unsigned)vb[j]);
            __syncthreads();   // S2: all poll1 loads retired block-wide

            // ===== PHASE D: layer-1 compute + publish =====
            const float4* h1v4 = (const float4*)hl1;
            float4 hr1[4];
            #pragma unroll
            for (int j = 0; j < 4; j++) hr1[j] = h1v4[64 * j + lane];

            float si[3], sh[3];
            #pragma unroll
            for (int g = 0; g < 3; g++) {
                const float4* wi = (const float4*)&lds[(wv * 9 + 3 + g) * HID];
                const float4* wh = (const float4*)&lds[(wv * 9 + 6 + g) * HID];
                float4 a = {0.f, 0.f, 0.f, 0.f};
                float4 c = {0.f, 0.f, 0.f, 0.f};
                #pragma unroll
                for (int j = 0; j < 4; j++) {
                    float4 w1 = wi[64 * j + lane];
                    float4 w2 = wh[64 * j + lane];
                    a.x += w1.x * hr0[j].x; a.y += w1.y * hr0[j].y;
                    a.z += w1.z * hr0[j].z; a.w += w1.w * hr0[j].w;
                    c.x += w2.x * hr1[j].x; c.y += w2.y * hr1[j].y;
                    c.z += w2.z * hr1[j].z; c.w += w2.w * hr1[j].w;
                }
                float ai = (a.x + a.y) + (a.z + a.w);
                float ch = (c.x + c.y) + (c.z + c.w);
                #pragma unroll
                for (int off = 32; off; off >>= 1) {
                    ai += __shfl_down(ai, off, 64);
                    ch += __shfl_down(ch, off, 64);
                }
                si[g] = ai; sh[g] = ch;
            }
            if (lane == 0) {
                const float r = 1.f / (1.f + __expf(-(si[0] + bi10 + sh[0] + bh10)));
                const float z = 1.f / (1.f + __expf(-(si[1] + bi11 + sh[1] + bh11)));
                const float nn = tanhf(si[2] + bi12 + r * (sh[2] + bh12));
                const float hnew = (1.f - z) * nn + z * hprev1;
                hprev1 = hnew;
                if (e <= T) {
                    const u64 v = ((u64)(unsigned)e << 32) | (u64)__float_as_uint(hnew);
                    __hip_atomic_store(&hbuf1[(e & 1) * HID + d], v,
                                       __ATOMIC_RELAXED, __HIP_MEMORY_SCOPE_AGENT);
                } else {
                    hout[d] = hnew;   // e == T+1: final h1
                }
            }
        }
    }
}

// ---------------------------------------------------------------------------
// out[o] = dot(fc_W[o,:], h) + fc_b[o]; 64 waves, 16 outputs each.
// ---------------------------------------------------------------------------
__global__ __launch_bounds__(256) void fc_kernel(
    const float* __restrict__ h, const float* __restrict__ W,
    const float* __restrict__ b, float* __restrict__ out)
{
    __shared__ float hs[HID];
    const int wv = blockIdx.x * 4 + (threadIdx.x >> 6);
    const int lane = threadIdx.x & 63;
    for (int i = threadIdx.x; i < HID; i += 256) hs[i] = h[i];
    __syncthreads();
    for (int o = wv * 16; o < wv * 16 + 16; o++) {
        float acc = 0.f;
        #pragma unroll
        for (int u = 0; u < 16; u++)
            acc += W[(size_t)o * HID + lane + 64 * u] * hs[lane + 64 * u];
        #pragma unroll
        for (int off = 32; off; off >>= 1)
            acc += __shfl_down(acc, off, 64);
        if (lane == 0) out[o] = acc + b[o];
    }
}

// ---------------------------------------------------------------------------
extern "C" void kernel_launch(void* const* d_in, const int* in_sizes, int n_in,
                              void* d_out, int out_size, void* d_ws, size_t ws_size,
                              hipStream_t stream)
{
    const float* node_feats = (const float*)d_in[0];
    const int*   node_types = (const int*)d_in[1];
    const float* W1   = (const float*)d_in[2];
    const float* b1   = (const float*)d_in[3];
    const float* W2   = (const float*)d_in[4];
    const float* b2   = (const float*)d_in[5];
    const float* Wih0 = (const float*)d_in[6];
    const float* Whh0 = (const float*)d_in[7];
    const float* bih0 = (const float*)d_in[8];
    const float* bhh0 = (const float*)d_in[9];
    const float* Wih1 = (const float*)d_in[10];
    const float* Whh1 = (const float*)d_in[11];
    const float* bih1 = (const float*)d_in[12];
    const float* bhh1 = (const float*)d_in[13];
    const float* h_init = (const float*)d_in[14];
    const float* fc_W = (const float*)d_in[15];
    const float* fc_b = (const float*)d_in[16];
    float* out = (float*)d_out;

    char* ws = (char*)d_ws;
    const size_t GI_OFF    = 0;                      // 8192*3072*4 = 100663296
    const size_t EMB_OFF   = 100663296;              // 8192*512*4  = 16777216
    const size_t HOUT_OFF  = 117440512;              // 1024*4      = 4096
    const size_t HBUF0_OFF = 117444608;              // 2048*8      = 16384
    const size_t HBUF1_OFF = 117460992;              // 2048*8      = 16384

    float* gi   = (float*)(ws + GI_OFF);
    float* emb  = (float*)(ws + EMB_OFF);
    float* hout = (float*)(ws + HOUT_OFF);
    u64* hbuf0  = (u64*)(ws + HBUF0_OFF);
    u64* hbuf1  = (u64*)(ws + HBUF1_OFF);
    // hbufs start 0xAA-poisoned: tag 0xAAAAAAAA never matches an epoch in
    // [1, 8193], so no memset needed anywhere.

    // 1. Expert MLP -> emb [8192, 512]
    mlp_kernel<<<N_NODES, 256, 0, stream>>>(node_feats, node_types, W1, b1, W2, b2, emb);

    // 2. gi0 = emb @ Wih0^T + bih0  [8192, 3072]
    gemm_bt_bias<<<dim3(G3 / BN, N_NODES / BM), 256, 0, stream>>>(
        emb, Wih0, bih0, gi, N_NODES, G3, EMB);

    // 3. fused 2-layer scan (split-phase throttled exchange)
    gru_fused<<<256, 256, 0, stream>>>(gi, Whh0, bhh0, Wih1, bih1, Whh1, bhh1,
                                       h_init, hbuf0, hbuf1, hout, SEQ);

    // 4. FC on final hidden state
    fc_kernel<<<16, 256, 0, stream>>>(hout, fc_W, fc_b, out);
}